// Round 8
// baseline (921.070 us; speedup 1.0000x reference)
//
#include <hip/hip_runtime.h>
#include <math.h>

typedef __bf16 bf16x8 __attribute__((ext_vector_type(8)));
typedef float  f32x4  __attribute__((ext_vector_type(4)));
typedef unsigned long long u64;
typedef u64 u64x2 __attribute__((ext_vector_type(2)));

__device__ __forceinline__ float gelu_f(float x) {
  const float k0 = 0.7978845608028654f;
  const float k1 = 0.044715f;
  float x3 = x * x * x;
  return 0.5f * x * (1.0f + tanhf(k0 * (x + k1 * x3)));
}

// coherent (agent-scope, IF$-backed) accessors: bypass non-coherent per-XCD L2
__device__ __forceinline__ u64 cload8(const void* p) {
  return __hip_atomic_load((u64*)p, __ATOMIC_RELAXED, __HIP_MEMORY_SCOPE_AGENT);
}
__device__ __forceinline__ void cstore_bf16(__bf16* p, __bf16 h) {
  __hip_atomic_store((short*)p, __builtin_bit_cast(short, h),
                     __ATOMIC_RELAXED, __HIP_MEMORY_SCOPE_AGENT);
}

// ---------------- prep: pool + weight transposes + Wv pack + y conv + beff ----------------
__global__ __launch_bounds__(256) void prep_kernel(
    const float* __restrict__ xe,
    const float* __restrict__ Wpi, const float* __restrict__ Wpa,
    const float* __restrict__ Wc,  const float* __restrict__ w1f,
    const float* __restrict__ w2f, const float* __restrict__ wo,
    const float* __restrict__ wqkv, const float* __restrict__ y,
    const float* __restrict__ bqkv, const float* __restrict__ bo,
    __bf16* __restrict__ xp_b,
    __bf16* __restrict__ WpiT, __bf16* __restrict__ WpaT,
    __bf16* __restrict__ WcabT, __bf16* __restrict__ WccT,
    __bf16* __restrict__ w1T,  __bf16* __restrict__ w2T,
    __bf16* __restrict__ woT,  __bf16* __restrict__ Wv_b,
    __bf16* __restrict__ y_b,  float* __restrict__ beff)
{
  int bid = blockIdx.x;
  int tid = threadIdx.x;
  if (bid < 512) {               // mean pool (128,512,1024) -> (128,1024) bf16
    int b = bid >> 2;
    int c = (bid & 3) * 256 + tid;
    const float* p = xe + (size_t)b * 512 * 1024 + c;
    float s = 0.f;
#pragma unroll 16
    for (int i = 0; i < 512; ++i) s += p[(size_t)i * 1024];
    xp_b[b * 1024 + c] = (__bf16)(s * (1.f / 512.f));
  } else if (bid < 6528) {       // transposes fp32 -> bf16 (N x K layout)
    int t = bid - 512;
    const float* src; __bf16* dst; int R, C;
    if      (t < 512)  {            src = Wpi;            dst = WpiT;          R = 1024; C = 512;  }
    else if (t < 640)  { t -= 512;  src = Wpa;            dst = WpaT;          R = 256;  C = 512;  }
    else if (t < 1152) { t -= 640;  src = Wc;             dst = WcabT;         R = 1024; C = 512;  }
    else if (t < 1408) { t -= 1152; src = Wc + 1024*512;  dst = WccT;          R = 512;  C = 512;  }
    else if (t < 2432) { t -= 1408; src = w1f;            dst = w1T;           R = 512;  C = 2048; }
    else if (t < 3456) { t -= 2432; src = w1f + 512*2048; dst = w1T + 1048576; R = 512;  C = 2048; }
    else if (t < 4480) { t -= 3456; src = w2f;            dst = w2T;           R = 2048; C = 512;  }
    else if (t < 5504) { t -= 4480; src = w2f + 2048*512; dst = w2T + 1048576; R = 2048; C = 512;  }
    else if (t < 5760) { t -= 5504; src = wo;             dst = woT;           R = 512;  C = 512;  }
    else               { t -= 5760; src = wo + 512*512;   dst = woT + 262144;  R = 512;  C = 512;  }
    int nbc = C / 32;
    int r0 = (t / nbc) * 32;
    int c0 = (t % nbc) * 32;
    __shared__ float tt[32][33];
    int tx = tid & 31, ty = tid >> 5;
#pragma unroll
    for (int i = 0; i < 32; i += 8)
      tt[ty + i][tx] = src[(size_t)(r0 + ty + i) * C + c0 + tx];
    __syncthreads();
#pragma unroll
    for (int i = 0; i < 32; i += 8)
      dst[(size_t)(c0 + ty + i) * R + r0 + tx] = (__bf16)tt[tx][ty + i];
  } else if (bid < 6784) {       // Wv pack
    int e0 = ((bid - 6528) * 256 + tid) * 8;
    int l = e0 >> 18, rem = e0 & 262143;
    int m = rem >> 9, k = rem & 511;
    const float* s = wqkv + (size_t)l * 786432 + (size_t)m * 1536 + 1024 + k;
#pragma unroll
    for (int j = 0; j < 8; ++j) Wv_b[e0 + j] = (__bf16)s[j];
  } else if (bid < 6800) {       // y -> bf16
    int e0 = ((bid - 6784) * 256 + tid) * 8;
#pragma unroll
    for (int j = 0; j < 8; ++j) y_b[e0 + j] = (__bf16)y[e0 + j];
  } else {                       // beff[l] = bv @ wo + bo
    int b2 = bid - 6800;
    int l = b2 >> 1;
    int n = (b2 & 1) * 256 + tid;
    const float* bv = bqkv + l * 1536 + 1024;
    const float* w  = wo + (size_t)l * 262144;
    float s = bo[l * 512 + n];
#pragma unroll 8
    for (int k = 0; k < 512; ++k) s += bv[k] * w[(size_t)k * 512 + n];
    beff[l * 512 + n] = s;
  }
}

// ---------------- LDS-tile GEMM (aux only) ----------------
template<int NT, bool BIAS>
__device__ __forceinline__ void gemm32(
    const __bf16* A, const __bf16* Bt, int bm0, int bn0,
    const float* bias, __bf16* outb, int ldo,
    __bf16* AL, __bf16* BL)
{
  const int tid = threadIdx.x;
  constexpr int K = NT * 64;
  const int row = tid >> 3;
  const int kcol = (tid & 7) * 8;

  const __bf16* Ab0 = A + (size_t)(bm0 + row) * K + kcol;
  const __bf16* Bb0 = Bt + (size_t)(bn0 + row) * K + kcol;

  u64 ra0[4], ra1[4], rb0[4], rb1[4];
  auto issue = [&](int t, int s) {
    const __bf16* ap = Ab0 + t * 64;
    const __bf16* bp = Bb0 + t * 64;
    ra0[s] = *(const u64*)ap; ra1[s] = *(const u64*)(ap + 4);
    rb0[s] = *(const u64*)bp; rb1[s] = *(const u64*)(bp + 4);
  };
#pragma unroll
  for (int s = 0; s < 4; ++s) issue(s, s);

  f32x4 acc = {0.f, 0.f, 0.f, 0.f};
  const int wave = tid >> 6, lane = tid & 63;
  const int wr = (wave >> 1) * 16, wc = (wave & 1) * 16;
  const int lr = lane & 15, lk8 = (lane >> 4) * 8;

  for (int ttc = 0; ttc < NT / 4; ++ttc) {
#pragma unroll
    for (int ti = 0; ti < 4; ++ti) {
      const int t = ttc * 4 + ti;
      __bf16* al = AL + (ti & 1) * 2304 + row * 72 + kcol;
      __bf16* bl = BL + (ti & 1) * 2304 + row * 72 + kcol;
      *(u64*)al = ra0[ti]; *(u64*)(al + 4) = ra1[ti];
      *(u64*)bl = rb0[ti]; *(u64*)(bl + 4) = rb1[ti];
      __syncthreads();
      if (t + 4 < NT) issue(t + 4, ti);
      const __bf16* Ar = AL + (ti & 1) * 2304 + (wr + lr) * 72;
      const __bf16* Br = BL + (ti & 1) * 2304 + (wc + lr) * 72;
      bf16x8 a0 = *(const bf16x8*)(Ar + lk8);
      bf16x8 b0v = *(const bf16x8*)(Br + lk8);
      acc = __builtin_amdgcn_mfma_f32_16x16x32_bf16(a0, b0v, acc, 0, 0, 0);
      bf16x8 a1 = *(const bf16x8*)(Ar + 32 + lk8);
      bf16x8 b1v = *(const bf16x8*)(Br + 32 + lk8);
      acc = __builtin_amdgcn_mfma_f32_16x16x32_bf16(a1, b1v, acc, 0, 0, 0);
      __syncthreads();
    }
  }

  const int er = bm0 + wr + (lane >> 4) * 4;
  const int ec = bn0 + wc + lr;
#pragma unroll
  for (int e = 0; e < 4; ++e) {
    float v = acc[e];
    if (BIAS) v += bias[ec];
    outb[(size_t)(er + e) * ldo + ec] = (__bf16)v;
  }
}

// ---------------- aux: Weff GEMMs + projections ----------------
__global__ __launch_bounds__(256) void aux_kernel(
    const __bf16* __restrict__ woT, const __bf16* __restrict__ Wv_b,
    const __bf16* __restrict__ xp_b, const __bf16* __restrict__ y_b,
    const __bf16* __restrict__ WpiT, const __bf16* __restrict__ WpaT,
    const float* __restrict__ bpi, const float* __restrict__ bpa,
    __bf16* __restrict__ WeffT, __bf16* __restrict__ xy_b)
{
  __shared__ __bf16 AL[2 * 32 * 72];
  __shared__ __bf16 BL[2 * 32 * 72];
  int bid = blockIdx.x;
  if (bid < 512) {        // WeffT[l][n][j] = sum_m woT[l][n][m] * Wv_b[l][j][m]
    int l = bid >> 8, t = bid & 255;
    gemm32<8, false>(woT + l * 262144, Wv_b + l * 262144,
        (t >> 4) * 32, (t & 15) * 32, nullptr, WeffT + l * 262144, 512, AL, BL);
  } else if (bid < 576) { // xy[:, :512] = xp @ Wpi + bpi
    int t = bid - 512;
    gemm32<16, true>(xp_b, WpiT, (t >> 4) * 32, (t & 15) * 32,
        bpi, xy_b, 1024, AL, BL);
  } else {                // xy[:, 512:] = y @ Wpa + bpa
    int t = bid - 576;
    gemm32<4, true>(y_b, WpaT, (t >> 4) * 32, (t & 15) * 32,
        bpa, xy_b + 512, 1024, AL, BL);
  }
}

// ---------------- 8-WG group barrier: own slot store + all-to-all poll ----------------
__device__ __forceinline__ void gbar(int* slots, int p, int ep) {
  asm volatile("s_waitcnt vmcnt(0)" ::: "memory");
  __syncthreads();
  if (threadIdx.x == 0)
    __hip_atomic_store(slots + p * 32, ep, __ATOMIC_RELAXED, __HIP_MEMORY_SCOPE_AGENT);
  if (threadIdx.x < 8) {
    while (__hip_atomic_load(slots + threadIdx.x * 32, __ATOMIC_RELAXED,
                             __HIP_MEMORY_SCOPE_AGENT) < ep)
      __builtin_amdgcn_s_sleep(1);
  }
  __syncthreads();
}

// ---------------- 16x16-tile GEMM core: A fully in regs, optional in-reg LN ----------------
// acc[NTILE] += [LN(A)] @ Bt^T tile(s). A: [128][KT*32] row-major; Bt: [N][KT*32] row-major.
template<int KT, int NTILE, bool LN_, bool COHA>
__device__ __forceinline__ void mm16(
    const __bf16* __restrict__ A, const __bf16* __restrict__ Bt,
    int am0, int bn0, int bnstep,
    const float* __restrict__ lng, const float* __restrict__ lnb,
    f32x4* __restrict__ acc)
{
  const int lane = threadIdx.x & 63;
  const int rc = lane & 15;
  const int k8 = (lane >> 4) * 8;
  constexpr int K = KT * 32;
  const __bf16* ap = A + (size_t)(am0 + rc) * K + k8;
  bf16x8 a[KT];
#pragma unroll
  for (int t = 0; t < KT; ++t) {
    if (COHA) {
      u64x2 q; q.x = cload8(ap + t * 32); q.y = cload8(ap + t * 32 + 4);
      a[t] = __builtin_bit_cast(bf16x8, q);
    } else {
      a[t] = *(const bf16x8*)(ap + t * 32);
    }
  }
  if (LN_) {
    float s = 0.f, s2 = 0.f;
#pragma unroll
    for (int t = 0; t < KT; ++t)
#pragma unroll
      for (int j = 0; j < 8; ++j) { float f = (float)a[t][j]; s += f; s2 += f * f; }
    s += __shfl_xor(s, 16); s2 += __shfl_xor(s2, 16);
    s += __shfl_xor(s, 32); s2 += __shfl_xor(s2, 32);
    float mu = s / (float)K;
    float rs = rsqrtf(s2 / (float)K - mu * mu + 1e-5f);
#pragma unroll
    for (int t = 0; t < KT; ++t) {
      const int kb = t * 32 + k8;
      f32x4 g0 = *(const f32x4*)(lng + kb);
      f32x4 g1 = *(const f32x4*)(lng + kb + 4);
      f32x4 b0 = *(const f32x4*)(lnb + kb);
      f32x4 b1 = *(const f32x4*)(lnb + kb + 4);
#pragma unroll
      for (int j = 0; j < 4; ++j) {
        a[t][j]     = (__bf16)(((float)a[t][j]     - mu) * rs * g0[j] + b0[j]);
        a[t][j + 4] = (__bf16)(((float)a[t][j + 4] - mu) * rs * g1[j] + b1[j]);
      }
    }
  }
#pragma unroll
  for (int nt = 0; nt < NTILE; ++nt) {
    const __bf16* bp = Bt + (size_t)(bn0 + nt * bnstep + rc) * K + k8;
    constexpr int W = KT < 16 ? KT : 16;
    bf16x8 b[W];
#pragma unroll
    for (int s = 0; s < W; ++s) b[s] = *(const bf16x8*)(bp + s * 32);
    f32x4 c = acc[nt];
#pragma unroll
    for (int t = 0; t < KT; ++t) {
      c = __builtin_amdgcn_mfma_f32_16x16x32_bf16(a[t], b[t % W], c, 0, 0, 0);
      if (t + W < KT) b[t % W] = *(const bf16x8*)(bp + (t + W) * 32);
    }
    acc[nt] = c;
  }
}

// ---------------- persistent mega kernel: 8 groups x 16 rows, residuals in registers ---------
__global__ __launch_bounds__(256, 1) void mega_kernel(
    const __bf16* __restrict__ xy_b, const __bf16* __restrict__ WcabT,
    const __bf16* __restrict__ WccT, const __bf16* __restrict__ WeffT,
    const __bf16* __restrict__ w1T, const __bf16* __restrict__ w2T,
    const float* __restrict__ bc, const float* __restrict__ beff,
    const float* __restrict__ ln1g, const float* __restrict__ ln1b,
    const float* __restrict__ ln2g, const float* __restrict__ ln2b,
    const float* __restrict__ b1f, const float* __restrict__ b2f,
    __bf16* c_b, __bf16* xb2, __bf16* xb4, __bf16* u_b, __bf16* z_b,
    float* out, int* bar)
{
  const int wg = blockIdx.x;
  const int g = wg >> 3, p = wg & 7;        // group (rows), rank (col-slice; == XCD under %8 map)
  const int wv = threadIdx.x >> 6;
  const int lane = threadIdx.x & 63;
  const int am0 = g * 16;
  const int cn  = p * 64 + wv * 16;         // 64-col stages: this wave's 16-col tile
  const int cn3 = p * 256 + wv * 64;        // S3: this wave's 4x16-col tiles
  int* slots = bar + g * 256;
  int ep = 0;

  const int col  = cn + (lane & 15);
  const int row0 = am0 + ((lane >> 4) << 2);

  f32x4 base_p, c_p, x_p, z_p = {0.f, 0.f, 0.f, 0.f};

  // BASE: c = xy @ Wcab + bc  (kept in regs as base_p; bf16 copy to c_b)
  {
    f32x4 acc = {0.f, 0.f, 0.f, 0.f};
    mm16<32, 1, false, false>(xy_b, WcabT, am0, cn, 0, nullptr, nullptr, &acc);
#pragma unroll
    for (int e = 0; e < 4; ++e) {
      float v = acc[e] + bc[col];
      base_p[e] = v;
      cstore_bf16(c_b + (size_t)(row0 + e) * 512 + col, (__bf16)v);
    }
  }
  gbar(slots, p, ++ep);

  for (int r = 0; r < 6; ++r) {
    if (r > 0) {  // S1: c = base + z @ Wcc
      f32x4 acc = {0.f, 0.f, 0.f, 0.f};
      mm16<16, 1, false, true>(z_b, WccT, am0, cn, 0, nullptr, nullptr, &acc);
#pragma unroll
      for (int e = 0; e < 4; ++e) {
        float v = base_p[e] + acc[e];
        c_p[e] = v;
        cstore_bf16(c_b + (size_t)(row0 + e) * 512 + col, (__bf16)v);
      }
      gbar(slots, p, ++ep);
    } else {
      c_p = base_p;
    }
#pragma unroll
    for (int l = 0; l < 2; ++l) {
      const __bf16* Ain = l ? xb4 : c_b;
      // S2: x = resid + LN1(A) @ Weff + beff   (resid in regs)
      {
        f32x4 acc = {0.f, 0.f, 0.f, 0.f};
        mm16<16, 1, true, true>(Ain, WeffT + l * 262144, am0, cn, 0,
                                ln1g + l * 512, ln1b + l * 512, &acc);
#pragma unroll
        for (int e = 0; e < 4; ++e) {
          float v = acc[e] + beff[l * 512 + col] + (l ? x_p[e] : c_p[e]);
          if (l) c_p[e] = v; else x_p[e] = v;
          cstore_bf16(xb2 + (size_t)(row0 + e) * 512 + col, (__bf16)v);
        }
        gbar(slots, p, ++ep);
      }
      // S3: u = gelu(LN2(x) @ w1 + b1)   (4 tiles per wave, A/stats loaded once)
      {
        f32x4 acc[4] = {{0.f,0.f,0.f,0.f},{0.f,0.f,0.f,0.f},
                        {0.f,0.f,0.f,0.f},{0.f,0.f,0.f,0.f}};
        mm16<16, 4, true, true>(xb2, w1T + l * 1048576, am0, cn3, 16,
                                ln2g + l * 512, ln2b + l * 512, acc);
#pragma unroll
        for (int nt = 0; nt < 4; ++nt) {
          const int c3 = cn3 + nt * 16 + (lane & 15);
#pragma unroll
          for (int e = 0; e < 4; ++e) {
            float v = gelu_f(acc[nt][e] + b1f[l * 2048 + c3]);
            cstore_bf16(u_b + (size_t)(row0 + e) * 2048 + c3, (__bf16)v);
          }
        }
        gbar(slots, p, ++ep);
      }
      // S4: x = x + u @ w2 + b2 ; l==1 accumulates into z (r==5 -> d_out)
      {
        f32x4 acc = {0.f, 0.f, 0.f, 0.f};
        mm16<64, 1, false, true>(u_b, w2T + l * 1048576, am0, cn, 0,
                                 nullptr, nullptr, &acc);
        if (l == 0) {
#pragma unroll
          for (int e = 0; e < 4; ++e) {
            float v = acc[e] + b2f[col] + x_p[e];
            x_p[e] = v;
            cstore_bf16(xb4 + (size_t)(row0 + e) * 512 + col, (__bf16)v);
          }
          gbar(slots, p, ++ep);
        } else {
#pragma unroll
          for (int e = 0; e < 4; ++e) {
            float v = acc[e] + b2f[512 + col] + c_p[e];
            z_p[e] += v;
          }
          if (r < 5) {
#pragma unroll
            for (int e = 0; e < 4; ++e)
              cstore_bf16(z_b + (size_t)(row0 + e) * 512 + col, (__bf16)z_p[e]);
            gbar(slots, p, ++ep);
          } else {
#pragma unroll
            for (int e = 0; e < 4; ++e)
              out[(size_t)(row0 + e) * 512 + col] = z_p[e];
          }
        }
      }
    }
  }
}

extern "C" void kernel_launch(void* const* d_in, const int* in_sizes, int n_in,
                              void* d_out, int out_size, void* d_ws, size_t ws_size,
                              hipStream_t stream) {
  const float* x_encoded = (const float*)d_in[0];
  const float* y_current = (const float*)d_in[1];
  const float* Wpi  = (const float*)d_in[2];
  const float* bpi  = (const float*)d_in[3];
  const float* Wpa  = (const float*)d_in[4];
  const float* bpa  = (const float*)d_in[5];
  const float* Wc   = (const float*)d_in[6];
  const float* bc   = (const float*)d_in[7];
  const float* ln1g = (const float*)d_in[8];
  const float* ln1b = (const float*)d_in[9];
  const float* wqkv = (const float*)d_in[10];
  const float* bqkv = (const float*)d_in[11];
  const float* wo   = (const float*)d_in[12];
  const float* bo   = (const float*)d_in[13];
  const float* ln2g = (const float*)d_in[14];
  const float* ln2b = (const float*)d_in[15];
  const float* w1f  = (const float*)d_in[16];
  const float* b1f  = (const float*)d_in[17];
  const float* w2f  = (const float*)d_in[18];
  const float* b2f  = (const float*)d_in[19];
  (void)in_sizes; (void)n_in; (void)out_size; (void)ws_size;

  char* wsb = (char*)d_ws;
  size_t off = 0;
  auto carve = [&](size_t bytes) -> void* {
    void* p = wsb + off;
    off += (bytes + 255) & ~(size_t)255;
    return p;
  };
  __bf16* xp_b    = (__bf16*)carve(131072 * 2);
  __bf16* y_b     = (__bf16*)carve(32768 * 2);
  __bf16* WpiT    = (__bf16*)carve(524288 * 2);
  __bf16* WpaT    = (__bf16*)carve(131072 * 2);
  __bf16* WcabT   = (__bf16*)carve(524288 * 2);
  __bf16* WccT    = (__bf16*)carve(262144 * 2);
  __bf16* w1T     = (__bf16*)carve(2097152 * 2);
  __bf16* w2T     = (__bf16*)carve(2097152 * 2);
  __bf16* woT     = (__bf16*)carve(524288 * 2);
  __bf16* Wv_b    = (__bf16*)carve(524288 * 2);
  __bf16* WeffT   = (__bf16*)carve(524288 * 2);
  float*  beff    = (float*) carve(1024 * 4);
  __bf16* xy_b    = (__bf16*)carve(131072 * 2);
  __bf16* c_b     = (__bf16*)carve(65536 * 2);
  __bf16* xb2     = (__bf16*)carve(65536 * 2);
  __bf16* xb4     = (__bf16*)carve(65536 * 2);
  __bf16* u_b     = (__bf16*)carve(262144 * 2);
  __bf16* z_b     = (__bf16*)carve(65536 * 2);
  int*    d_bar   = (int*)   carve(16384);

  hipMemsetAsync(d_bar, 0, 16384, stream);
  prep_kernel<<<6804, 256, 0, stream>>>(x_encoded, Wpi, Wpa, Wc, w1f, w2f, wo,
      wqkv, y_current, bqkv, bo, xp_b, WpiT, WpaT, WcabT, WccT, w1T, w2T, woT,
      Wv_b, y_b, beff);
  aux_kernel<<<640, 256, 0, stream>>>(woT, Wv_b, xp_b, y_b, WpiT, WpaT,
      bpi, bpa, WeffT, xy_b);
  mega_kernel<<<64, 256, 0, stream>>>(
      xy_b, WcabT, WccT, WeffT, w1T, w2T, bc, beff,
      ln1g, ln1b, ln2g, ln2b, b1f, b2f,
      c_b, xb2, xb4, u_b, z_b,
      (float*)d_out, d_bar);
}